// Round 1
// baseline (847.330 us; speedup 1.0000x reference)
//
#include <hip/hip_runtime.h>
#include <cstddef>
#include <cmath>

// Problem constants
#define NROWS 16384   // 32*512
#define DIM   512
#define KC    2048

// d_out layout (float32 element offsets)
#define Q_OFF    0ul
#define LOSS_OFF 8388608ul    // 33,554,432 elems  (reused as sim scratch)
#define NN_OFF   41943040ul   // 16,384 elems
#define CB_OFF   41959424ul   // 1,048,576 elems   (reused as diversity partials [512][2048])
#define CNT_OFF  43008000ul   // 2,048 elems

// ---------------------------------------------------------------- init ws ---
__global__ __launch_bounds__(256) void init_ws(int* __restrict__ ws) {
    int t = blockIdx.x * 256 + threadIdx.x;
    if (t < 2052) ws[t] = 0;   // loss scalar + pad + counts[2048]
}

// ---------------------------------------------------------------- GEMM ------
// sim[n][k] = sum_d A[n][d] * B[k][d];  A [16384,512], B [2048,512] row-major
__global__ __launch_bounds__(256) void gemm_sim(const float* __restrict__ A,
                                                const float* __restrict__ B,
                                                float* __restrict__ C) {
    __shared__ float As[32][68];   // [d][m], pad 64->68 (16B-aligned rows, low conflict)
    __shared__ float Bs[32][68];   // [d][n]
    const int t  = threadIdx.x;
    const int tx = t & 15, ty = t >> 4;
    const int ty4 = ty << 2, tx4 = tx << 2;
    const int row0 = blockIdx.x * 64;
    const int col0 = blockIdx.y * 64;

    float acc[4][4] = {};

    for (int d0 = 0; d0 < DIM; d0 += 32) {
        #pragma unroll
        for (int l = 0; l < 2; ++l) {
            int f  = t + l * 256;        // 0..511
            int r  = f >> 3;             // 0..63
            int c4 = (f & 7) << 2;       // 0,4,...,28
            float4 va = *(const float4*)(A + (size_t)(row0 + r) * DIM + d0 + c4);
            As[c4 + 0][r] = va.x; As[c4 + 1][r] = va.y;
            As[c4 + 2][r] = va.z; As[c4 + 3][r] = va.w;
            float4 vb = *(const float4*)(B + (size_t)(col0 + r) * DIM + d0 + c4);
            Bs[c4 + 0][r] = vb.x; Bs[c4 + 1][r] = vb.y;
            Bs[c4 + 2][r] = vb.z; Bs[c4 + 3][r] = vb.w;
        }
        __syncthreads();
        #pragma unroll
        for (int dc = 0; dc < 32; ++dc) {
            float a0 = As[dc][ty4 + 0], a1 = As[dc][ty4 + 1];
            float a2 = As[dc][ty4 + 2], a3 = As[dc][ty4 + 3];
            float b0 = Bs[dc][tx4 + 0], b1 = Bs[dc][tx4 + 1];
            float b2 = Bs[dc][tx4 + 2], b3 = Bs[dc][tx4 + 3];
            acc[0][0] += a0 * b0; acc[0][1] += a0 * b1; acc[0][2] += a0 * b2; acc[0][3] += a0 * b3;
            acc[1][0] += a1 * b0; acc[1][1] += a1 * b1; acc[1][2] += a1 * b2; acc[1][3] += a1 * b3;
            acc[2][0] += a2 * b0; acc[2][1] += a2 * b1; acc[2][2] += a2 * b2; acc[2][3] += a2 * b3;
            acc[3][0] += a3 * b0; acc[3][1] += a3 * b1; acc[3][2] += a3 * b2; acc[3][3] += a3 * b3;
        }
        __syncthreads();
    }
    #pragma unroll
    for (int i = 0; i < 4; ++i) {
        float4 v = make_float4(acc[i][0], acc[i][1], acc[i][2], acc[i][3]);
        *(float4*)(C + (size_t)(row0 + ty4 + i) * KC + col0 + tx4) = v;
    }
}

// ------------------------------------------------------------ block reduce --
__device__ __forceinline__ float block_reduce_sum(float v, volatile float* sf,
                                                  int lane, int w) {
    #pragma unroll
    for (int off = 32; off; off >>= 1) v += __shfl_xor(v, off, 64);
    if (lane == 0) sf[w] = v;
    __syncthreads();
    v = sf[0] + sf[1] + sf[2] + sf[3];
    __syncthreads();
    return v;
}

// ---------------------------------------------------------------- row pass --
// Per row: argmax (first-occurrence ties), softmax (max-sub), entropy term,
// diversity partial. Deterministic: block partials, no fp atomics.
__global__ __launch_bounds__(256) void rowpass(const float* __restrict__ sim,
                                               float* __restrict__ nn,
                                               float* __restrict__ divpart,   // [512][2048]
                                               int*   __restrict__ counts,    // ws [2048]
                                               float* __restrict__ entpart) { // ws [512]
    __shared__ float divp[KC];
    __shared__ float sf[4];
    __shared__ float sv[4];
    __shared__ int   si[4];
    const int t = threadIdx.x;
    const int lane = t & 63, w = t >> 6;
    const int b = blockIdx.x;

    for (int j = t; j < KC; j += 256) divp[j] = 0.f;
    __syncthreads();

    float ent_acc = 0.f;
    for (int rr = 0; rr < 32; ++rr) {
        const int row = b * 32 + rr;
        const float* srow = sim + (size_t)row * KC;
        float s[8];
        #pragma unroll
        for (int j = 0; j < 8; ++j) s[j] = srow[t + 256 * j];

        // (max, argmax) with first-occurrence tie rule
        float bv = s[0]; int bi = t;
        #pragma unroll
        for (int j = 1; j < 8; ++j)
            if (s[j] > bv) { bv = s[j]; bi = t + 256 * j; }
        #pragma unroll
        for (int off = 32; off; off >>= 1) {
            float ov = __shfl_xor(bv, off, 64);
            int   oi = __shfl_xor(bi, off, 64);
            if (ov > bv || (ov == bv && oi < bi)) { bv = ov; bi = oi; }
        }
        if (lane == 0) { sv[w] = bv; si[w] = bi; }
        __syncthreads();
        float m = sv[0]; int idx = si[0];
        #pragma unroll
        for (int k = 1; k < 4; ++k) {
            float v2 = sv[k]; int i2 = si[k];
            if (v2 > m || (v2 == m && i2 < idx)) { m = v2; idx = i2; }
        }
        __syncthreads();

        float e[8]; float ls = 0.f;
        #pragma unroll
        for (int j = 0; j < 8; ++j) { e[j] = expf(s[j] - m); ls += e[j]; }
        float Z = block_reduce_sum(ls, sf, lane, w);
        float inv = 1.0f / Z;

        float lent = 0.f;
        #pragma unroll
        for (int j = 0; j < 8; ++j) {
            float p = e[j] * inv;
            divp[t + 256 * j] += p;               // each thread owns its slots
            lent += p * log2f(p + 1e-8f);
        }
        float rent = block_reduce_sum(lent, sf, lane, w);
        if (t == 0) {
            ent_acc += rent;
            atomicAdd(&counts[idx], 1);
            nn[row] = (float)idx;
        }
    }
    __syncthreads();
    for (int j = t; j < KC; j += 256) divpart[(size_t)b * KC + j] = divp[j];
    if (t == 0) entpart[b] = ent_acc;
}

// --------------------------------------------------------------- finalize ---
__global__ __launch_bounds__(256) void finalize(const float* __restrict__ divpart,
                                                const float* __restrict__ entpart,
                                                float* __restrict__ lossp) {
    __shared__ float sf[4];
    const int t = threadIdx.x, lane = t & 63, w = t >> 6;
    float a0x=0,a0y=0,a0z=0,a0w=0, a1x=0,a1y=0,a1z=0,a1w=0;
    const float4* p4 = (const float4*)divpart;
    for (int r = 0; r < 512; ++r) {
        float4 u = p4[(size_t)r * 512 + t];
        float4 v = p4[(size_t)r * 512 + t + 256];
        a0x += u.x; a0y += u.y; a0z += u.z; a0w += u.w;
        a1x += v.x; a1y += v.y; a1z += v.z; a1w += v.w;
    }
    const float scl = 1.0f / 16384.0f;
    float loc = 0.f;
    {
        float d;
        d = a0x*scl; loc += d*log2f(d+1e-8f);  d = a0y*scl; loc += d*log2f(d+1e-8f);
        d = a0z*scl; loc += d*log2f(d+1e-8f);  d = a0w*scl; loc += d*log2f(d+1e-8f);
        d = a1x*scl; loc += d*log2f(d+1e-8f);  d = a1y*scl; loc += d*log2f(d+1e-8f);
        d = a1z*scl; loc += d*log2f(d+1e-8f);  d = a1w*scl; loc += d*log2f(d+1e-8f);
    }
    float Sd = block_reduce_sum(loc, sf, lane, w);            // sum div*log2(div+eps)
    float Se = block_reduce_sum(entpart[t] + entpart[t + 256], sf, lane, w);
    if (t == 0) {
        // loss = h_clust - GAMMA*h_div = -Se/N + Sd   (GAMMA = 1)
        lossp[0] = (float)(-(double)Se / 16384.0 + (double)Sd);
    }
}

// --------------------------------------------------------------- quantize ---
__global__ __launch_bounds__(256) void quantize_rows(const float* __restrict__ x,
                                                     const float* __restrict__ cb,
                                                     const float* __restrict__ nn,
                                                     float* __restrict__ qout) {
    const int lane = threadIdx.x & 63;
    const int row  = (blockIdx.x << 2) + (threadIdx.x >> 6);
    const int idx  = (int)nn[row];
    const float* c  = cb + (size_t)idx * DIM;
    const float* xr = x  + (size_t)row * DIM;

    float4 q0 = *(const float4*)(c + lane * 8);
    float4 q1 = *(const float4*)(c + lane * 8 + 4);

    float s = q0.x+q0.y+q0.z+q0.w + q1.x+q1.y+q1.z+q1.w;
    #pragma unroll
    for (int off = 32; off; off >>= 1) s += __shfl_xor(s, off, 64);
    const float mean = s * (1.0f / 512.0f);
    q0.x -= mean; q0.y -= mean; q0.z -= mean; q0.w -= mean;
    q1.x -= mean; q1.y -= mean; q1.z -= mean; q1.w -= mean;

    float ss = q0.x*q0.x+q0.y*q0.y+q0.z*q0.z+q0.w*q0.w
             + q1.x*q1.x+q1.y*q1.y+q1.z*q1.z+q1.w*q1.w;
    #pragma unroll
    for (int off = 32; off; off >>= 1) ss += __shfl_xor(ss, off, 64);
    const float inv = 1.0f / sqrtf(ss);

    float4 x0 = *(const float4*)(xr + lane * 8);
    float4 x1 = *(const float4*)(xr + lane * 8 + 4);
    float4 o0, o1;   // STE: x + (q_norm - x)
    o0.x = x0.x + (q0.x*inv - x0.x); o0.y = x0.y + (q0.y*inv - x0.y);
    o0.z = x0.z + (q0.z*inv - x0.z); o0.w = x0.w + (q0.w*inv - x0.w);
    o1.x = x1.x + (q1.x*inv - x1.x); o1.y = x1.y + (q1.y*inv - x1.y);
    o1.z = x1.z + (q1.z*inv - x1.z); o1.w = x1.w + (q1.w*inv - x1.w);
    *(float4*)(qout + (size_t)row * DIM + lane * 8)     = o0;
    *(float4*)(qout + (size_t)row * DIM + lane * 8 + 4) = o1;
}

// --------------------------------------------------------------- epilogue ---
__global__ __launch_bounds__(256) void epilogue(float* __restrict__ out,
                                                const float* __restrict__ cb,
                                                const float* __restrict__ oldc,
                                                const int*   __restrict__ counts,
                                                const float* __restrict__ lossp,
                                                const int*   __restrict__ train) {
    const size_t LOSS4 = 33554432ul / 4;  // 8,388,608
    const size_t CB4   = 1048576ul  / 4;  //   262,144
    size_t i = (size_t)blockIdx.x * 256 + threadIdx.x;
    if (i < LOSS4) {
        const float l = lossp[0];
        ((float4*)(out + LOSS_OFF))[i] = make_float4(l, l, l, l);
    } else if (i < LOSS4 + CB4) {
        size_t j = i - LOSS4;
        ((float4*)(out + CB_OFF))[j] = ((const float4*)cb)[j];
    } else {
        size_t k = i - LOSS4 - CB4;
        if (k < 2048) {
            float nc = train[0] ? 0.99f * oldc[k] + 0.01f * (float)counts[k]
                                : oldc[k];
            out[CNT_OFF + k] = nc;
        }
    }
}

// ------------------------------------------------------------------ launch --
extern "C" void kernel_launch(void* const* d_in, const int* in_sizes, int n_in,
                              void* d_out, int out_size, void* d_ws, size_t ws_size,
                              hipStream_t stream) {
    const float* x     = (const float*)d_in[0];
    const float* cb    = (const float*)d_in[1];
    const float* oldc  = (const float*)d_in[2];
    const int*   train = (const int*)d_in[3];
    float* out = (float*)d_out;

    float* sim     = out + LOSS_OFF;   // scratch in loss region
    float* divpart = out + CB_OFF;     // scratch in codebook-copy region
    float* nn      = out + NN_OFF;

    float* lossp   = (float*)d_ws;          // [0]
    int*   counts  = (int*)d_ws + 4;        // [4..2051]
    float* entpart = (float*)d_ws + 2052;   // [2052..2563]

    init_ws<<<9, 256, 0, stream>>>((int*)d_ws);
    gemm_sim<<<dim3(NROWS / 64, KC / 64), 256, 0, stream>>>(x, cb, sim);
    rowpass<<<NROWS / 32, 256, 0, stream>>>(sim, nn, divpart, counts, entpart);
    finalize<<<1, 256, 0, stream>>>(divpart, entpart, lossp);
    quantize_rows<<<NROWS / 4, 256, 0, stream>>>(x, cb, nn, out);
    epilogue<<<33800, 256, 0, stream>>>(out, cb, oldc, counts, lossp, train);
}

// Round 2
// 450.001 us; speedup vs baseline: 1.8829x; 1.8829x over previous
//
#include <hip/hip_runtime.h>
#include <cstddef>
#include <cmath>

// Problem constants
#define NROWS 16384   // 32*512
#define DIM   512
#define KC    2048

// d_out layout (float32 element offsets)
#define Q_OFF    0ul
#define LOSS_OFF 8388608ul    // 33,554,432 elems  (reused as sim scratch)
#define NN_OFF   41943040ul   // 16,384 elems
#define CB_OFF   41959424ul   // 1,048,576 elems   (reused as diversity partials [512][2048])
#define CNT_OFF  43008000ul   // 2,048 elems

#define FLAG_CAP 4096

typedef __attribute__((ext_vector_type(8))) short short8;
typedef __attribute__((ext_vector_type(4))) float f32x4;

// ---------------------------------------------------------------- init ws ---
__global__ __launch_bounds__(256) void init_ws(int* __restrict__ ws) {
    int t = blockIdx.x * 256 + threadIdx.x;
    if (t < 2052 || t == 2564) ws[t] = 0;   // loss + counts[2048], nflag
}

// ----------------------------------------------------------- bf16 split -----
__device__ __forceinline__ short hi1(float f) {
    return (short)(__float_as_uint(f) >> 16);
}
__device__ __forceinline__ short lo1(float f) {
    unsigned int u = __float_as_uint(f);
    float l = f - __uint_as_float(u & 0xffff0000u);
    return (short)(__float_as_uint(l) >> 16);
}
__device__ __forceinline__ short8 hi8(float4 a, float4 b) {
    short8 r;
    r[0]=hi1(a.x); r[1]=hi1(a.y); r[2]=hi1(a.z); r[3]=hi1(a.w);
    r[4]=hi1(b.x); r[5]=hi1(b.y); r[6]=hi1(b.z); r[7]=hi1(b.w);
    return r;
}
__device__ __forceinline__ short8 lo8(float4 a, float4 b) {
    short8 r;
    r[0]=lo1(a.x); r[1]=lo1(a.y); r[2]=lo1(a.z); r[3]=lo1(a.w);
    r[4]=lo1(b.x); r[5]=lo1(b.y); r[6]=lo1(b.z); r[7]=lo1(b.w);
    return r;
}

// ---------------------------------------------------------------- GEMM ------
// sim[n][k] = A[16384,512] x B[2048,512]^T via bf16 hi/lo 3-term split MFMA.
// Tile 128x128xBK32, 4 waves (2x2), each wave 64x64 = 4x4 mfma_16x16x32 tiles.
#define LDW  40      // ushort row stride (80 B: conflict-free b128 phases)
#define AH_B 0
#define AL_B 5120
#define BH_B 10240
#define BL_B 15360

__global__ __launch_bounds__(256, 3) void gemm_mfma(const float* __restrict__ A,
                                                    const float* __restrict__ B,
                                                    float* __restrict__ C) {
    __shared__ ushort smem[20480];   // 40 KB
    const int t    = threadIdx.x;
    const int n0   = blockIdx.x * 128;
    const int m0   = blockIdx.y * 128;
    const int rsub = t >> 2;            // 0..63
    const int kc   = (t & 3) * 8;       // 0,8,16,24
    const int lane = t & 63, quad = lane >> 4, lr = lane & 15;
    const int w = t >> 6, wm = w >> 1, wn = w & 1;

    f32x4 acc[4][4] = {};

    const float* Abase = A + (size_t)(m0 + rsub) * DIM + kc;
    const float* Bbase = B + (size_t)(n0 + rsub) * DIM + kc;

    float4 pa0 = *(const float4*)(Abase);
    float4 pa1 = *(const float4*)(Abase + 4);
    float4 pa2 = *(const float4*)(Abase + 64 * DIM);
    float4 pa3 = *(const float4*)(Abase + 64 * DIM + 4);
    float4 pb0 = *(const float4*)(Bbase);
    float4 pb1 = *(const float4*)(Bbase + 4);
    float4 pb2 = *(const float4*)(Bbase + 64 * DIM);
    float4 pb3 = *(const float4*)(Bbase + 64 * DIM + 4);

    ushort* wa0 = smem + AH_B + rsub * LDW + kc;
    ushort* wa1 = smem + AH_B + (rsub + 64) * LDW + kc;
    ushort* wb0 = smem + BH_B + rsub * LDW + kc;
    ushort* wb1 = smem + BH_B + (rsub + 64) * LDW + kc;

    const ushort* ra = smem + (wm * 64 + lr) * LDW + quad * 8;
    const ushort* rb = smem + (wn * 64 + lr) * LDW + quad * 8;

    for (int kk = 0; kk < 16; ++kk) {
        // convert + stage current K-chunk
        *(short8*)(wa0)        = hi8(pa0, pa1);
        *(short8*)(wa0 + AL_B) = lo8(pa0, pa1);
        *(short8*)(wa1)        = hi8(pa2, pa3);
        *(short8*)(wa1 + AL_B) = lo8(pa2, pa3);
        *(short8*)(wb0)        = hi8(pb0, pb1);
        *(short8*)(wb0 + AL_B) = lo8(pb0, pb1);   // BL = BH + 5120 too
        *(short8*)(wb1)        = hi8(pb2, pb3);
        *(short8*)(wb1 + AL_B) = lo8(pb2, pb3);
        __syncthreads();

        // prefetch next K-chunk (lands during MFMAs)
        if (kk < 15) {
            const float* a = Abase + (kk + 1) * 32;
            const float* b = Bbase + (kk + 1) * 32;
            pa0 = *(const float4*)(a);
            pa1 = *(const float4*)(a + 4);
            pa2 = *(const float4*)(a + 64 * DIM);
            pa3 = *(const float4*)(a + 64 * DIM + 4);
            pb0 = *(const float4*)(b);
            pb1 = *(const float4*)(b + 4);
            pb2 = *(const float4*)(b + 64 * DIM);
            pb3 = *(const float4*)(b + 64 * DIM + 4);
        }

        short8 ah[4], al[4], bx[4];
        #pragma unroll
        for (int mt = 0; mt < 4; ++mt) ah[mt] = *(const short8*)(ra + AH_B + mt * 16 * LDW);
        #pragma unroll
        for (int nt = 0; nt < 4; ++nt) bx[nt] = *(const short8*)(rb + BH_B + nt * 16 * LDW);
        #pragma unroll
        for (int mt = 0; mt < 4; ++mt)
            #pragma unroll
            for (int nt = 0; nt < 4; ++nt)
                acc[mt][nt] = __builtin_amdgcn_mfma_f32_16x16x32_bf16(ah[mt], bx[nt], acc[mt][nt], 0, 0, 0);
        #pragma unroll
        for (int mt = 0; mt < 4; ++mt) al[mt] = *(const short8*)(ra + AL_B + mt * 16 * LDW);
        #pragma unroll
        for (int mt = 0; mt < 4; ++mt)
            #pragma unroll
            for (int nt = 0; nt < 4; ++nt)
                acc[mt][nt] = __builtin_amdgcn_mfma_f32_16x16x32_bf16(al[mt], bx[nt], acc[mt][nt], 0, 0, 0);
        #pragma unroll
        for (int nt = 0; nt < 4; ++nt) bx[nt] = *(const short8*)(rb + BL_B + nt * 16 * LDW);
        #pragma unroll
        for (int mt = 0; mt < 4; ++mt)
            #pragma unroll
            for (int nt = 0; nt < 4; ++nt)
                acc[mt][nt] = __builtin_amdgcn_mfma_f32_16x16x32_bf16(ah[mt], bx[nt], acc[mt][nt], 0, 0, 0);
        __syncthreads();
    }

    // epilogue: C[row=quad*4+j][col=lane&15] per 16x16 tile (verified layout)
    #pragma unroll
    for (int mt = 0; mt < 4; ++mt) {
        #pragma unroll
        for (int nt = 0; nt < 4; ++nt) {
            const int r0 = m0 + wm * 64 + mt * 16 + quad * 4;
            const int c0 = n0 + wn * 64 + nt * 16 + lr;
            #pragma unroll
            for (int j = 0; j < 4; ++j)
                C[(size_t)(r0 + j) * KC + c0] = acc[mt][nt][j];
        }
    }
}

// ------------------------------------------------------------ block reduce --
__device__ __forceinline__ float block_reduce_sum(float v, volatile float* sf,
                                                  int lane, int w) {
    #pragma unroll
    for (int off = 32; off; off >>= 1) v += __shfl_xor(v, off, 64);
    if (lane == 0) sf[w] = v;
    __syncthreads();
    v = sf[0] + sf[1] + sf[2] + sf[3];
    __syncthreads();
    return v;
}

// ---------------------------------------------------------------- row pass --
__global__ __launch_bounds__(256) void rowpass(const float* __restrict__ sim,
                                               float* __restrict__ nn,
                                               float* __restrict__ divpart,   // [512][2048]
                                               int*   __restrict__ counts,    // ws [2048]
                                               float* __restrict__ entpart,   // ws [512]
                                               int*   __restrict__ nflag,
                                               int*   __restrict__ flags) {
    __shared__ float divp[KC];
    __shared__ float sf[4];
    __shared__ float sv[4];
    __shared__ int   si[4];
    __shared__ float sv2[4];
    __shared__ int   si2[4];
    const int t = threadIdx.x;
    const int lane = t & 63, w = t >> 6;
    const int b = blockIdx.x;

    for (int j = t; j < KC; j += 256) divp[j] = 0.f;
    __syncthreads();

    float ent_acc = 0.f;
    for (int rr = 0; rr < 32; ++rr) {
        const int row = b * 32 + rr;
        const float* srow = sim + (size_t)row * KC;
        float s[8];
        #pragma unroll
        for (int j = 0; j < 8; ++j) s[j] = srow[t + 256 * j];

        // (max, argmax) with first-occurrence tie rule
        float bv = s[0]; int bi = t;
        #pragma unroll
        for (int j = 1; j < 8; ++j)
            if (s[j] > bv) { bv = s[j]; bi = t + 256 * j; }
        #pragma unroll
        for (int off = 32; off; off >>= 1) {
            float ov = __shfl_xor(bv, off, 64);
            int   oi = __shfl_xor(bi, off, 64);
            if (ov > bv || (ov == bv && oi < bi)) { bv = ov; bi = oi; }
        }
        if (lane == 0) { sv[w] = bv; si[w] = bi; }
        __syncthreads();
        float m = sv[0]; int idx = si[0];
        #pragma unroll
        for (int k = 1; k < 4; ++k) {
            float v2 = sv[k]; int i2 = si[k];
            if (v2 > m || (v2 == m && i2 < idx)) { m = v2; idx = i2; }
        }
        __syncthreads();

        // runner-up (excluding idx) -> flag near-ties for exact fixup
        float rv = -3.0e38f; int ri = 0x7fffffff;
        #pragma unroll
        for (int j = 0; j < 8; ++j) {
            int gi = t + 256 * j;
            if (gi != idx && (s[j] > rv || (s[j] == rv && gi < ri))) { rv = s[j]; ri = gi; }
        }
        #pragma unroll
        for (int off = 32; off; off >>= 1) {
            float ov = __shfl_xor(rv, off, 64);
            int   oi = __shfl_xor(ri, off, 64);
            if (ov > rv || (ov == rv && oi < ri)) { rv = ov; ri = oi; }
        }
        if (lane == 0) { sv2[w] = rv; si2[w] = ri; }
        __syncthreads();
        if (t == 0) {
            float rm = sv2[0]; int rix = si2[0];
            #pragma unroll
            for (int k = 1; k < 4; ++k)
                if (sv2[k] > rm || (sv2[k] == rm && si2[k] < rix)) { rm = sv2[k]; rix = si2[k]; }
            if (m - rm < 3e-5f) {
                int e = atomicAdd(nflag, 1);
                if (e < FLAG_CAP) { flags[3*e] = row; flags[3*e+1] = idx; flags[3*e+2] = rix; }
            }
        }

        float e[8]; float ls = 0.f;
        #pragma unroll
        for (int j = 0; j < 8; ++j) { e[j] = expf(s[j] - m); ls += e[j]; }
        float Z = block_reduce_sum(ls, sf, lane, w);
        float inv = 1.0f / Z;

        float lent = 0.f;
        #pragma unroll
        for (int j = 0; j < 8; ++j) {
            float p = e[j] * inv;
            divp[t + 256 * j] += p;
            lent += p * log2f(p + 1e-8f);
        }
        float rent = block_reduce_sum(lent, sf, lane, w);
        if (t == 0) {
            ent_acc += rent;
            atomicAdd(&counts[idx], 1);
            nn[row] = (float)idx;
        }
        __syncthreads();
    }
    for (int j = t; j < KC; j += 256) divpart[(size_t)b * KC + j] = divp[j];
    if (t == 0) entpart[b] = ent_acc;
}

// ----------------------------------------------------------------- fixup ----
// Recompute exact fp32 dots for flagged near-tie rows; correct nn + counts.
__global__ __launch_bounds__(256) void fixup(const float* __restrict__ A,
                                             const float* __restrict__ B,
                                             float* __restrict__ nn,
                                             int*   __restrict__ counts,
                                             const int* __restrict__ flags,
                                             const int* __restrict__ nflagp) {
    __shared__ float sf[4];
    int nf = *nflagp; if (nf > FLAG_CAP) nf = FLAG_CAP;
    const int t = threadIdx.x, lane = t & 63, w = t >> 6;
    for (int e = blockIdx.x; e < nf; e += gridDim.x) {
        const int row = flags[3*e], i1 = flags[3*e+1], i2 = flags[3*e+2];
        const float* ar = A + (size_t)row * DIM;
        const float* b1 = B + (size_t)i1 * DIM;
        const float* b2 = B + (size_t)i2 * DIM;
        float d1 = ar[t] * b1[t] + ar[t + 256] * b1[t + 256];
        float d2 = ar[t] * b2[t] + ar[t + 256] * b2[t + 256];
        d1 = block_reduce_sum(d1, sf, lane, w);
        d2 = block_reduce_sum(d2, sf, lane, w);
        if (t == 0 && (d2 > d1 || (d2 == d1 && i2 < i1))) {
            nn[row] = (float)i2;
            atomicSub(&counts[i1], 1);
            atomicAdd(&counts[i2], 1);
        }
        __syncthreads();
    }
}

// ------------------------------------------------------------- finalize -----
__global__ __launch_bounds__(256) void finalize_part(const float* __restrict__ divpart,
                                                     float* __restrict__ divlogp) {
    __shared__ float sf[4];
    const int t = threadIdx.x, lane = t & 63, w = t >> 6;
    const int k = blockIdx.x * 256 + t;
    float s = 0.f;
    for (int r = 0; r < 512; ++r) s += divpart[(size_t)r * KC + k];
    float d = s * (1.0f / 16384.0f);
    float v = d * log2f(d + 1e-8f);
    float S = block_reduce_sum(v, sf, lane, w);
    if (t == 0) divlogp[blockIdx.x] = S;
}

__global__ __launch_bounds__(256) void finalize2(const float* __restrict__ entpart,
                                                 const float* __restrict__ divlogp,
                                                 float* __restrict__ lossp) {
    __shared__ float sf[4];
    const int t = threadIdx.x, lane = t & 63, w = t >> 6;
    float Se = block_reduce_sum(entpart[t] + entpart[t + 256], sf, lane, w);
    float Sd = block_reduce_sum((t < 8) ? divlogp[t] : 0.f, sf, lane, w);
    if (t == 0)
        lossp[0] = (float)(-(double)Se / 16384.0 + (double)Sd);
}

// --------------------------------------------------------------- quantize ---
__global__ __launch_bounds__(256) void quantize_rows(const float* __restrict__ x,
                                                     const float* __restrict__ cb,
                                                     const float* __restrict__ nn,
                                                     float* __restrict__ qout) {
    const int lane = threadIdx.x & 63;
    const int row  = (blockIdx.x << 2) + (threadIdx.x >> 6);
    const int idx  = (int)nn[row];
    const float* c  = cb + (size_t)idx * DIM;
    const float* xr = x  + (size_t)row * DIM;

    float4 q0 = *(const float4*)(c + lane * 8);
    float4 q1 = *(const float4*)(c + lane * 8 + 4);

    float s = q0.x+q0.y+q0.z+q0.w + q1.x+q1.y+q1.z+q1.w;
    #pragma unroll
    for (int off = 32; off; off >>= 1) s += __shfl_xor(s, off, 64);
    const float mean = s * (1.0f / 512.0f);
    q0.x -= mean; q0.y -= mean; q0.z -= mean; q0.w -= mean;
    q1.x -= mean; q1.y -= mean; q1.z -= mean; q1.w -= mean;

    float ss = q0.x*q0.x+q0.y*q0.y+q0.z*q0.z+q0.w*q0.w
             + q1.x*q1.x+q1.y*q1.y+q1.z*q1.z+q1.w*q1.w;
    #pragma unroll
    for (int off = 32; off; off >>= 1) ss += __shfl_xor(ss, off, 64);
    const float inv = 1.0f / sqrtf(ss);

    float4 x0 = *(const float4*)(xr + lane * 8);
    float4 x1 = *(const float4*)(xr + lane * 8 + 4);
    float4 o0, o1;   // STE: x + (q_norm - x)
    o0.x = x0.x + (q0.x*inv - x0.x); o0.y = x0.y + (q0.y*inv - x0.y);
    o0.z = x0.z + (q0.z*inv - x0.z); o0.w = x0.w + (q0.w*inv - x0.w);
    o1.x = x1.x + (q1.x*inv - x1.x); o1.y = x1.y + (q1.y*inv - x1.y);
    o1.z = x1.z + (q1.z*inv - x1.z); o1.w = x1.w + (q1.w*inv - x1.w);
    *(float4*)(qout + (size_t)row * DIM + lane * 8)     = o0;
    *(float4*)(qout + (size_t)row * DIM + lane * 8 + 4) = o1;
}

// --------------------------------------------------------------- epilogue ---
__global__ __launch_bounds__(256) void epilogue(float* __restrict__ out,
                                                const float* __restrict__ cb,
                                                const float* __restrict__ oldc,
                                                const int*   __restrict__ counts,
                                                const float* __restrict__ lossp,
                                                const int*   __restrict__ train) {
    const size_t LOSS4 = 33554432ul / 4;  // 8,388,608
    const size_t CB4   = 1048576ul  / 4;  //   262,144
    size_t i = (size_t)blockIdx.x * 256 + threadIdx.x;
    if (i < LOSS4) {
        const float l = lossp[0];
        ((float4*)(out + LOSS_OFF))[i] = make_float4(l, l, l, l);
    } else if (i < LOSS4 + CB4) {
        size_t j = i - LOSS4;
        ((float4*)(out + CB_OFF))[j] = ((const float4*)cb)[j];
    } else {
        size_t k = i - LOSS4 - CB4;
        if (k < 2048) {
            float nc = train[0] ? 0.99f * oldc[k] + 0.01f * (float)counts[k]
                                : oldc[k];
            out[CNT_OFF + k] = nc;
        }
    }
}

// ------------------------------------------------------------------ launch --
extern "C" void kernel_launch(void* const* d_in, const int* in_sizes, int n_in,
                              void* d_out, int out_size, void* d_ws, size_t ws_size,
                              hipStream_t stream) {
    const float* x     = (const float*)d_in[0];
    const float* cb    = (const float*)d_in[1];
    const float* oldc  = (const float*)d_in[2];
    const int*   train = (const int*)d_in[3];
    float* out = (float*)d_out;

    float* sim     = out + LOSS_OFF;   // scratch in loss region
    float* divpart = out + CB_OFF;     // scratch in codebook-copy region
    float* nn      = out + NN_OFF;

    float* lossp   = (float*)d_ws;            // [0]
    int*   counts  = (int*)d_ws + 4;          // [4..2051]
    float* entpart = (float*)d_ws + 2052;     // [2052..2563]
    int*   nflag   = (int*)d_ws + 2564;
    int*   flags   = (int*)d_ws + 2568;       // 3*4096 ints
    float* divlogp = (float*)d_ws + 14856;    // [8]

    init_ws<<<11, 256, 0, stream>>>((int*)d_ws);
    gemm_mfma<<<dim3(KC / 128, NROWS / 128), 256, 0, stream>>>(x, cb, sim);
    rowpass<<<NROWS / 32, 256, 0, stream>>>(sim, nn, divpart, counts, entpart, nflag, flags);
    fixup<<<32, 256, 0, stream>>>(x, cb, nn, counts, flags, nflag);
    finalize_part<<<KC / 256, 256, 0, stream>>>(divpart, divlogp);
    finalize2<<<1, 256, 0, stream>>>(entpart, divlogp, lossp);
    quantize_rows<<<NROWS / 4, 256, 0, stream>>>(x, cb, nn, out);
    epilogue<<<33800, 256, 0, stream>>>(out, cb, oldc, counts, lossp, train);
}

// Round 3
// 371.573 us; speedup vs baseline: 2.2804x; 1.2111x over previous
//
#include <hip/hip_runtime.h>
#include <cstddef>
#include <cmath>

// Problem constants
#define NROWS 16384   // 32*512
#define DIM   512
#define KC    2048

// d_out layout (float32 element offsets)
#define Q_OFF    0ul          // 8,388,608 elems (reused as divpart2 [1024][2048])
#define LOSS_OFF 8388608ul    // 33,554,432 elems (reused as sim scratch)
#define NN_OFF   41943040ul   // 16,384 elems
#define CB_OFF   41959424ul   // 1,048,576 elems (reused as part2 [128][2048])
#define CNT_OFF  43008000ul   // 2,048 elems

#define FLAG_CAP 4096

// ws layout (32-bit slots)
#define WS_LOSS   0
#define WS_CNT    4       // 2048 ints
#define WS_ENT    2052    // 1024 floats
#define WS_NFLAG  3076
#define WS_FLAGS  3080    // 3*4096 ints
#define WS_DIVLOG 15376   // 8 floats

typedef __attribute__((ext_vector_type(8))) short short8;
typedef __attribute__((ext_vector_type(4))) float f32x4;

// ----------------------------------------------------------- bf16 split -----
__device__ __forceinline__ short hi1(float f) {
    return (short)(__float_as_uint(f) >> 16);
}
__device__ __forceinline__ short lo1(float f) {
    unsigned int u = __float_as_uint(f);
    float l = f - __uint_as_float(u & 0xffff0000u);
    return (short)(__float_as_uint(l) >> 16);
}
__device__ __forceinline__ short8 hi8(float4 a, float4 b) {
    short8 r;
    r[0]=hi1(a.x); r[1]=hi1(a.y); r[2]=hi1(a.z); r[3]=hi1(a.w);
    r[4]=hi1(b.x); r[5]=hi1(b.y); r[6]=hi1(b.z); r[7]=hi1(b.w);
    return r;
}
__device__ __forceinline__ short8 lo8(float4 a, float4 b) {
    short8 r;
    r[0]=lo1(a.x); r[1]=lo1(a.y); r[2]=lo1(a.z); r[3]=lo1(a.w);
    r[4]=lo1(b.x); r[5]=lo1(b.y); r[6]=lo1(b.z); r[7]=lo1(b.w);
    return r;
}

// ---------------------------------------------------------------- GEMM ------
// sim[n][k] = A[16384,512] x B[2048,512]^T via bf16 hi/lo 3-term split MFMA.
#define LDW  40
#define AH_B 0
#define AL_B 5120
#define BH_B 10240
#define BL_B 15360

__global__ __launch_bounds__(256, 3) void gemm_mfma(const float* __restrict__ A,
                                                    const float* __restrict__ B,
                                                    float* __restrict__ C,
                                                    int* __restrict__ ws) {
    // block (0,0) also zeroes the ws counters (visible to rowpass at kernel boundary)
    if (blockIdx.x == 0 && blockIdx.y == 0) {
        for (int i = threadIdx.x + WS_CNT; i < WS_CNT + 2048; i += 256) ws[i] = 0;
        if (threadIdx.x == 0) ws[WS_NFLAG] = 0;
    }
    __shared__ ushort smem[20480];   // 40 KB
    const int t    = threadIdx.x;
    const int n0   = blockIdx.x * 128;
    const int m0   = blockIdx.y * 128;
    const int rsub = t >> 2;
    const int kc   = (t & 3) * 8;
    const int lane = t & 63, quad = lane >> 4, lr = lane & 15;
    const int w = t >> 6, wm = w >> 1, wn = w & 1;

    f32x4 acc[4][4] = {};

    const float* Abase = A + (size_t)(m0 + rsub) * DIM + kc;
    const float* Bbase = B + (size_t)(n0 + rsub) * DIM + kc;

    float4 pa0 = *(const float4*)(Abase);
    float4 pa1 = *(const float4*)(Abase + 4);
    float4 pa2 = *(const float4*)(Abase + 64 * DIM);
    float4 pa3 = *(const float4*)(Abase + 64 * DIM + 4);
    float4 pb0 = *(const float4*)(Bbase);
    float4 pb1 = *(const float4*)(Bbase + 4);
    float4 pb2 = *(const float4*)(Bbase + 64 * DIM);
    float4 pb3 = *(const float4*)(Bbase + 64 * DIM + 4);

    ushort* wa0 = smem + AH_B + rsub * LDW + kc;
    ushort* wa1 = smem + AH_B + (rsub + 64) * LDW + kc;
    ushort* wb0 = smem + BH_B + rsub * LDW + kc;
    ushort* wb1 = smem + BH_B + (rsub + 64) * LDW + kc;

    const ushort* ra = smem + (wm * 64 + lr) * LDW + quad * 8;
    const ushort* rb = smem + (wn * 64 + lr) * LDW + quad * 8;

    for (int kk = 0; kk < 16; ++kk) {
        *(short8*)(wa0)        = hi8(pa0, pa1);
        *(short8*)(wa0 + AL_B) = lo8(pa0, pa1);
        *(short8*)(wa1)        = hi8(pa2, pa3);
        *(short8*)(wa1 + AL_B) = lo8(pa2, pa3);
        *(short8*)(wb0)        = hi8(pb0, pb1);
        *(short8*)(wb0 + AL_B) = lo8(pb0, pb1);
        *(short8*)(wb1)        = hi8(pb2, pb3);
        *(short8*)(wb1 + AL_B) = lo8(pb2, pb3);
        __syncthreads();

        if (kk < 15) {
            const float* a = Abase + (kk + 1) * 32;
            const float* b = Bbase + (kk + 1) * 32;
            pa0 = *(const float4*)(a);
            pa1 = *(const float4*)(a + 4);
            pa2 = *(const float4*)(a + 64 * DIM);
            pa3 = *(const float4*)(a + 64 * DIM + 4);
            pb0 = *(const float4*)(b);
            pb1 = *(const float4*)(b + 4);
            pb2 = *(const float4*)(b + 64 * DIM);
            pb3 = *(const float4*)(b + 64 * DIM + 4);
        }

        short8 ah[4], al[4], bx[4];
        #pragma unroll
        for (int mt = 0; mt < 4; ++mt) ah[mt] = *(const short8*)(ra + AH_B + mt * 16 * LDW);
        #pragma unroll
        for (int nt = 0; nt < 4; ++nt) bx[nt] = *(const short8*)(rb + BH_B + nt * 16 * LDW);
        #pragma unroll
        for (int mt = 0; mt < 4; ++mt)
            #pragma unroll
            for (int nt = 0; nt < 4; ++nt)
                acc[mt][nt] = __builtin_amdgcn_mfma_f32_16x16x32_bf16(ah[mt], bx[nt], acc[mt][nt], 0, 0, 0);
        #pragma unroll
        for (int mt = 0; mt < 4; ++mt) al[mt] = *(const short8*)(ra + AL_B + mt * 16 * LDW);
        #pragma unroll
        for (int mt = 0; mt < 4; ++mt)
            #pragma unroll
            for (int nt = 0; nt < 4; ++nt)
                acc[mt][nt] = __builtin_amdgcn_mfma_f32_16x16x32_bf16(al[mt], bx[nt], acc[mt][nt], 0, 0, 0);
        #pragma unroll
        for (int nt = 0; nt < 4; ++nt) bx[nt] = *(const short8*)(rb + BL_B + nt * 16 * LDW);
        #pragma unroll
        for (int mt = 0; mt < 4; ++mt)
            #pragma unroll
            for (int nt = 0; nt < 4; ++nt)
                acc[mt][nt] = __builtin_amdgcn_mfma_f32_16x16x32_bf16(ah[mt], bx[nt], acc[mt][nt], 0, 0, 0);
        __syncthreads();
    }

    #pragma unroll
    for (int mt = 0; mt < 4; ++mt) {
        #pragma unroll
        for (int nt = 0; nt < 4; ++nt) {
            const int r0 = m0 + wm * 64 + mt * 16 + quad * 4;
            const int c0 = n0 + wn * 64 + nt * 16 + lr;
            #pragma unroll
            for (int j = 0; j < 4; ++j)
                C[(size_t)(r0 + j) * KC + c0] = acc[mt][nt][j];
        }
    }
}

// ------------------------------------------------------------ block reduce --
__device__ __forceinline__ float block_reduce_sum(float v, volatile float* sf,
                                                  int lane, int w) {
    #pragma unroll
    for (int off = 32; off; off >>= 1) v += __shfl_xor(v, off, 64);
    if (lane == 0) sf[w] = v;
    __syncthreads();
    v = sf[0] + sf[1] + sf[2] + sf[3];
    __syncthreads();
    return v;
}

// ---------------------------------------------------------------- row pass --
// One row per wave per iteration: all row reductions are wave shuffles.
// Grid 1024 blocks x 16 rows (4 rows/wave). Diversity in registers, combined
// deterministically (w0+w1+w2+w3) -> divpart2[1024][2048] in the Q region.
// Entropy closed form: sum p*log2(p+eps) = log2e*S/Z - log2(Z) + K*eps*log2e.
__global__ __launch_bounds__(256, 4) void rowpass(const float* __restrict__ sim,
                                                  float* __restrict__ nn,
                                                  float* __restrict__ divpart2,  // [1024][2048]
                                                  int*   __restrict__ counts,
                                                  float* __restrict__ entpart,   // [1024]
                                                  int*   __restrict__ nflag,
                                                  int*   __restrict__ flags) {
    __shared__ float divp[KC];
    __shared__ float sent[4];
    const int t = threadIdx.x, lane = t & 63, w = t >> 6;
    const int b = blockIdx.x;
    const int row0 = b * 16 + w * 4;
    const int col0 = lane << 2;

    float4 dacc[8] = {};
    float ent_acc = 0.f;

    const float* base = sim + (size_t)row0 * KC + col0;
    float4 cur[8], nxt[8];
    #pragma unroll
    for (int j = 0; j < 8; ++j) cur[j] = *(const float4*)(base + 256 * j);

    for (int rr = 0; rr < 4; ++rr) {
        if (rr < 3) {
            const float* nb = base + (size_t)(rr + 1) * KC;
            #pragma unroll
            for (int j = 0; j < 8; ++j) nxt[j] = *(const float4*)(nb + 256 * j);
        }

        // ---- top-2 (value, index) with first-occurrence tie rule ----
        float bv = -3.0e38f, rv = -3.0e38f;
        int   bi = 0x7fffffff, ri = 0x7fffffff;
        #pragma unroll
        for (int j = 0; j < 8; ++j) {
            #pragma unroll
            for (int c = 0; c < 4; ++c) {
                float v = (&cur[j].x)[c];
                int   i = col0 + c + 256 * j;
                if (v > bv || (v == bv && i < bi)) { rv = bv; ri = bi; bv = v; bi = i; }
                else if (v > rv || (v == rv && i < ri)) { rv = v; ri = i; }
            }
        }
        #pragma unroll
        for (int off = 32; off; off >>= 1) {
            float obv = __shfl_xor(bv, off, 64);
            int   obi = __shfl_xor(bi, off, 64);
            float orv = __shfl_xor(rv, off, 64);
            int   ori = __shfl_xor(ri, off, 64);
            bool ob = (obv > bv) || (obv == bv && obi < bi);
            float c1v = ob ? bv : obv;  int c1i = ob ? bi : obi;   // loser best
            float c2v = ob ? orv : rv;  int c2i = ob ? ori : ri;   // winner's runner
            bv = ob ? obv : bv;  bi = ob ? obi : bi;
            bool rb = (c1v > c2v) || (c1v == c2v && c1i < c2i);
            rv = rb ? c1v : c2v;  ri = rb ? c1i : c2i;
        }
        const float m = bv;

        // ---- softmax stats: Z = sum e, S = sum e*(s-m);  e stored in cur ----
        float Z = 0.f, S = 0.f;
        #pragma unroll
        for (int j = 0; j < 8; ++j) {
            #pragma unroll
            for (int c = 0; c < 4; ++c) {
                float d = (&cur[j].x)[c] - m;
                float e = expf(d);
                Z += e; S += e * d;
                (&cur[j].x)[c] = e;
            }
        }
        #pragma unroll
        for (int off = 32; off; off >>= 1) {
            Z += __shfl_xor(Z, off, 64);
            S += __shfl_xor(S, off, 64);
        }
        const float inv = 1.0f / Z;
        #pragma unroll
        for (int j = 0; j < 8; ++j) {
            dacc[j].x += cur[j].x * inv; dacc[j].y += cur[j].y * inv;
            dacc[j].z += cur[j].z * inv; dacc[j].w += cur[j].w * inv;
        }

        if (lane == 0) {
            // sum p*log2(p+1e-8) = log2e*(S/Z) - log2(Z) + 2048*1e-8*log2e
            ent_acc += 1.4426950408889634f * (S * inv) - log2f(Z) + 2.9546393e-5f;
            atomicAdd(&counts[bi], 1);
            nn[row0 + rr] = (float)bi;
            if (bv - rv < 3e-5f) {
                int e = atomicAdd(nflag, 1);
                if (e < FLAG_CAP) {
                    flags[3*e] = row0 + rr; flags[3*e+1] = bi; flags[3*e+2] = ri;
                }
            }
        }

        if (rr < 3) {
            #pragma unroll
            for (int j = 0; j < 8; ++j) cur[j] = nxt[j];
        }
    }

    if (lane == 0) sent[w] = ent_acc;
    // deterministic cross-wave diversity combine: w0 store, w1..w3 add
    for (int ww = 0; ww < 4; ++ww) {
        if (w == ww) {
            #pragma unroll
            for (int j = 0; j < 8; ++j) {
                float4* p = (float4*)&divp[col0 + 256 * j];
                if (ww == 0) *p = dacc[j];
                else {
                    float4 v = *p;
                    v.x += dacc[j].x; v.y += dacc[j].y;
                    v.z += dacc[j].z; v.w += dacc[j].w;
                    *p = v;
                }
            }
        }
        __syncthreads();
    }
    float4* dst = (float4*)(divpart2 + (size_t)b * KC);
    dst[t]       = *(float4*)&divp[t * 4];
    dst[t + 256] = *(float4*)&divp[t * 4 + 1024];
    if (t == 0) entpart[b] = sent[0] + sent[1] + sent[2] + sent[3];
}

// ----------------------------------------------------------------- fixup ----
__global__ __launch_bounds__(256) void fixup(const float* __restrict__ A,
                                             const float* __restrict__ B,
                                             float* __restrict__ nn,
                                             int*   __restrict__ counts,
                                             const int* __restrict__ flags,
                                             const int* __restrict__ nflagp) {
    __shared__ float sf[4];
    int nf = *nflagp; if (nf > FLAG_CAP) nf = FLAG_CAP;
    const int t = threadIdx.x, lane = t & 63, w = t >> 6;
    for (int e = blockIdx.x; e < nf; e += gridDim.x) {
        const int row = flags[3*e], i1 = flags[3*e+1], i2 = flags[3*e+2];
        const float* ar = A + (size_t)row * DIM;
        const float* b1 = B + (size_t)i1 * DIM;
        const float* b2 = B + (size_t)i2 * DIM;
        float d1 = ar[t] * b1[t] + ar[t + 256] * b1[t + 256];
        float d2 = ar[t] * b2[t] + ar[t + 256] * b2[t + 256];
        d1 = block_reduce_sum(d1, sf, lane, w);
        d2 = block_reduce_sum(d2, sf, lane, w);
        if (t == 0 && (d2 > d1 || (d2 == d1 && i2 < i1))) {
            nn[row] = (float)i2;
            atomicSub(&counts[i1], 1);
            atomicAdd(&counts[i2], 1);
        }
        __syncthreads();
    }
}

// ------------------------------------------------------------- finalize -----
__global__ __launch_bounds__(256) void fin1a(const float* __restrict__ divpart2,
                                             float* __restrict__ part2) {  // [128][2048]
    const int t = threadIdx.x, b = blockIdx.x;
    const float* dp = divpart2 + (size_t)b * 8 * KC;
    #pragma unroll
    for (int j = 0; j < 8; ++j) {
        int c = t + 256 * j;
        float s = 0.f;
        #pragma unroll
        for (int r = 0; r < 8; ++r) s += dp[(size_t)r * KC + c];
        part2[(size_t)b * KC + c] = s;
    }
}

__global__ __launch_bounds__(256) void fin1b(const float* __restrict__ part2,
                                             float* __restrict__ divlog8) {
    __shared__ float sf[4];
    const int t = threadIdx.x, lane = t & 63, w = t >> 6;
    const int c = blockIdx.x * 256 + t;
    float s = 0.f;
    for (int r = 0; r < 128; ++r) s += part2[(size_t)r * KC + c];
    float d = s * (1.0f / 16384.0f);
    float v = d * log2f(d + 1e-8f);
    float S = block_reduce_sum(v, sf, lane, w);
    if (t == 0) divlog8[blockIdx.x] = S;
}

__global__ __launch_bounds__(256) void fin2(const float* __restrict__ entpart,
                                            const float* __restrict__ divlog8,
                                            float* __restrict__ lossp) {
    __shared__ float sf[4];
    const int t = threadIdx.x, lane = t & 63, w = t >> 6;
    float se = entpart[t] + entpart[t + 256] + entpart[t + 512] + entpart[t + 768];
    float Se = block_reduce_sum(se, sf, lane, w);
    float Sd = block_reduce_sum((t < 8) ? divlog8[t] : 0.f, sf, lane, w);
    if (t == 0)
        lossp[0] = (float)(-(double)Se / 16384.0 + (double)Sd);
}

// ------------------------------------------------------- quantize+epilogue --
__global__ __launch_bounds__(256) void tail(const float* __restrict__ x,
                                            const float* __restrict__ cb,
                                            const float* __restrict__ oldc,
                                            const int*   __restrict__ counts,
                                            const float* __restrict__ lossp,
                                            const int*   __restrict__ train,
                                            const float* __restrict__ nn,
                                            float* __restrict__ out) {
    const int bb = blockIdx.x;
    const int t  = threadIdx.x;
    if (bb < 4096) {
        // quantize 4 rows per block
        const int lane = t & 63;
        const int row  = (bb << 2) + (t >> 6);
        const int idx  = (int)nn[row];
        const float* c  = cb + (size_t)idx * DIM;
        const float* xr = x  + (size_t)row * DIM;

        float4 q0 = *(const float4*)(c + lane * 8);
        float4 q1 = *(const float4*)(c + lane * 8 + 4);

        float s = q0.x+q0.y+q0.z+q0.w + q1.x+q1.y+q1.z+q1.w;
        #pragma unroll
        for (int off = 32; off; off >>= 1) s += __shfl_xor(s, off, 64);
        const float mean = s * (1.0f / 512.0f);
        q0.x -= mean; q0.y -= mean; q0.z -= mean; q0.w -= mean;
        q1.x -= mean; q1.y -= mean; q1.z -= mean; q1.w -= mean;

        float ss = q0.x*q0.x+q0.y*q0.y+q0.z*q0.z+q0.w*q0.w
                 + q1.x*q1.x+q1.y*q1.y+q1.z*q1.z+q1.w*q1.w;
        #pragma unroll
        for (int off = 32; off; off >>= 1) ss += __shfl_xor(ss, off, 64);
        const float inv = 1.0f / sqrtf(ss);

        float4 x0 = *(const float4*)(xr + lane * 8);
        float4 x1 = *(const float4*)(xr + lane * 8 + 4);
        float4 o0, o1;   // STE: x + (q_norm - x)
        o0.x = x0.x + (q0.x*inv - x0.x); o0.y = x0.y + (q0.y*inv - x0.y);
        o0.z = x0.z + (q0.z*inv - x0.z); o0.w = x0.w + (q0.w*inv - x0.w);
        o1.x = x1.x + (q1.x*inv - x1.x); o1.y = x1.y + (q1.y*inv - x1.y);
        o1.z = x1.z + (q1.z*inv - x1.z); o1.w = x1.w + (q1.w*inv - x1.w);
        *(float4*)(out + (size_t)row * DIM + lane * 8)     = o0;
        *(float4*)(out + (size_t)row * DIM + lane * 8 + 4) = o1;
    } else {
        const size_t LOSS4 = 33554432ul / 4;
        const size_t CB4   = 1048576ul  / 4;
        size_t i = (size_t)(bb - 4096) * 256 + t;
        if (i < LOSS4) {
            const float l = lossp[0];
            ((float4*)(out + LOSS_OFF))[i] = make_float4(l, l, l, l);
        } else if (i < LOSS4 + CB4) {
            size_t j = i - LOSS4;
            ((float4*)(out + CB_OFF))[j] = ((const float4*)cb)[j];
        } else {
            size_t k = i - LOSS4 - CB4;
            if (k < 2048) {
                float nc = train[0] ? 0.99f * oldc[k] + 0.01f * (float)counts[k]
                                    : oldc[k];
                out[CNT_OFF + k] = nc;
            }
        }
    }
}

// ------------------------------------------------------------------ launch --
extern "C" void kernel_launch(void* const* d_in, const int* in_sizes, int n_in,
                              void* d_out, int out_size, void* d_ws, size_t ws_size,
                              hipStream_t stream) {
    const float* x     = (const float*)d_in[0];
    const float* cb    = (const float*)d_in[1];
    const float* oldc  = (const float*)d_in[2];
    const int*   train = (const int*)d_in[3];
    float* out = (float*)d_out;

    float* sim      = out + LOSS_OFF;  // sim scratch in loss region
    float* divpart2 = out + Q_OFF;     // [1024][2048] in quantized region
    float* part2    = out + CB_OFF;    // [128][2048] in codebook-copy region
    float* nn       = out + NN_OFF;

    float* lossp   = (float*)d_ws + WS_LOSS;
    int*   counts  = (int*)d_ws   + WS_CNT;
    float* entpart = (float*)d_ws + WS_ENT;
    int*   nflag   = (int*)d_ws   + WS_NFLAG;
    int*   flags   = (int*)d_ws   + WS_FLAGS;
    float* divlog8 = (float*)d_ws + WS_DIVLOG;

    gemm_mfma<<<dim3(KC / 128, NROWS / 128), 256, 0, stream>>>(x, cb, sim, (int*)d_ws);
    rowpass<<<1024, 256, 0, stream>>>(sim, nn, divpart2, counts, entpart, nflag, flags);
    fixup<<<64, 256, 0, stream>>>(x, cb, nn, counts, flags, nflag);
    fin1a<<<128, 256, 0, stream>>>(divpart2, part2);
    fin1b<<<8, 256, 0, stream>>>(part2, divlog8);
    fin2<<<1, 256, 0, stream>>>(entpart, divlog8, lossp);
    tail<<<4096 + 33800, 256, 0, stream>>>(x, cb, oldc, counts, lossp, train, nn, out);
}

// Round 5
// 356.933 us; speedup vs baseline: 2.3739x; 1.0410x over previous
//
#include <hip/hip_runtime.h>
#include <cstddef>
#include <cmath>

// Problem constants
#define NROWS 16384   // 32*512
#define DIM   512
#define KC    2048

// d_out layout (float32 element offsets)
#define Q_OFF    0ul          // 8,388,608 elems (reused as divpart2 [1024][2048])
#define LOSS_OFF 8388608ul    // 33,554,432 elems (reused as sim scratch)
#define NN_OFF   41943040ul   // 16,384 elems
#define CB_OFF   41959424ul   // 1,048,576 elems (reused as part2 [128][2048])
#define CNT_OFF  43008000ul   // 2,048 elems

#define FLAG_CAP 4096
#define FLAG_TAU 3e-5f        // 3-term split: observed argmax errors ~1e-6; 3e-5 passed r1-r3

// ws layout (32-bit slots)
#define WS_LOSS   0
#define WS_CNT    4       // 2048 ints
#define WS_ENT    2052    // 1024 floats
#define WS_NFLAG  3076
#define WS_FLAGS  3080    // 3*4096 ints
#define WS_DIVLOG 15376   // 8 floats

typedef __attribute__((ext_vector_type(8))) short short8;
typedef __attribute__((ext_vector_type(4))) float f32x4;

// ----------------------------------------------------------- bf16 split -----
__device__ __forceinline__ short hi1(float f) {
    return (short)(__float_as_uint(f) >> 16);
}
__device__ __forceinline__ short lo1(float f) {
    unsigned int u = __float_as_uint(f);
    float l = f - __uint_as_float(u & 0xffff0000u);
    return (short)(__float_as_uint(l) >> 16);
}
__device__ __forceinline__ short8 hi8(float4 a, float4 b) {
    short8 r;
    r[0]=hi1(a.x); r[1]=hi1(a.y); r[2]=hi1(a.z); r[3]=hi1(a.w);
    r[4]=hi1(b.x); r[5]=hi1(b.y); r[6]=hi1(b.z); r[7]=hi1(b.w);
    return r;
}
__device__ __forceinline__ short8 lo8(float4 a, float4 b) {
    short8 r;
    r[0]=lo1(a.x); r[1]=lo1(a.y); r[2]=lo1(a.z); r[3]=lo1(a.w);
    r[4]=lo1(b.x); r[5]=lo1(b.y); r[6]=lo1(b.z); r[7]=lo1(b.w);
    return r;
}

// ---------------------------------------------------------------- GEMM ------
// sim = A x B^T via bf16 hi/lo 3-term split: Ah*Bh + Al*Bh + Ah*Bl.
// (2-term was tried in r4 and broke argmax: band-exceeding near-ties. Keep 3.)
#define LDW  40
#define AH_B 0
#define AL_B 5120
#define BH_B 10240
#define BL_B 15360

__global__ __launch_bounds__(256, 3) void gemm_mfma(const float* __restrict__ A,
                                                    const float* __restrict__ B,
                                                    float* __restrict__ C,
                                                    int* __restrict__ ws) {
    if (blockIdx.x == 0 && blockIdx.y == 0) {
        for (int i = threadIdx.x + WS_CNT; i < WS_CNT + 2048; i += 256) ws[i] = 0;
        if (threadIdx.x == 0) ws[WS_NFLAG] = 0;
    }
    __shared__ ushort smem[20480];   // 40 KB
    const int t    = threadIdx.x;
    const int n0   = blockIdx.x * 128;
    const int m0   = blockIdx.y * 128;
    const int rsub = t >> 2;
    const int kc   = (t & 3) * 8;
    const int lane = t & 63, quad = lane >> 4, lr = lane & 15;
    const int w = t >> 6, wm = w >> 1, wn = w & 1;

    f32x4 acc[4][4] = {};

    const float* Abase = A + (size_t)(m0 + rsub) * DIM + kc;
    const float* Bbase = B + (size_t)(n0 + rsub) * DIM + kc;

    float4 pa0 = *(const float4*)(Abase);
    float4 pa1 = *(const float4*)(Abase + 4);
    float4 pa2 = *(const float4*)(Abase + 64 * DIM);
    float4 pa3 = *(const float4*)(Abase + 64 * DIM + 4);
    float4 pb0 = *(const float4*)(Bbase);
    float4 pb1 = *(const float4*)(Bbase + 4);
    float4 pb2 = *(const float4*)(Bbase + 64 * DIM);
    float4 pb3 = *(const float4*)(Bbase + 64 * DIM + 4);

    ushort* wa0 = smem + AH_B + rsub * LDW + kc;
    ushort* wa1 = smem + AH_B + (rsub + 64) * LDW + kc;
    ushort* wb0 = smem + BH_B + rsub * LDW + kc;
    ushort* wb1 = smem + BH_B + (rsub + 64) * LDW + kc;

    const ushort* ra = smem + (wm * 64 + lr) * LDW + quad * 8;
    const ushort* rb = smem + (wn * 64 + lr) * LDW + quad * 8;

    for (int kk = 0; kk < 16; ++kk) {
        *(short8*)(wa0)        = hi8(pa0, pa1);
        *(short8*)(wa0 + AL_B) = lo8(pa0, pa1);
        *(short8*)(wa1)        = hi8(pa2, pa3);
        *(short8*)(wa1 + AL_B) = lo8(pa2, pa3);
        *(short8*)(wb0)        = hi8(pb0, pb1);
        *(short8*)(wb0 + AL_B) = lo8(pb0, pb1);
        *(short8*)(wb1)        = hi8(pb2, pb3);
        *(short8*)(wb1 + AL_B) = lo8(pb2, pb3);
        __syncthreads();

        if (kk < 15) {
            const float* a = Abase + (kk + 1) * 32;
            const float* b = Bbase + (kk + 1) * 32;
            pa0 = *(const float4*)(a);
            pa1 = *(const float4*)(a + 4);
            pa2 = *(const float4*)(a + 64 * DIM);
            pa3 = *(const float4*)(a + 64 * DIM + 4);
            pb0 = *(const float4*)(b);
            pb1 = *(const float4*)(b + 4);
            pb2 = *(const float4*)(b + 64 * DIM);
            pb3 = *(const float4*)(b + 64 * DIM + 4);
        }

        short8 ah[4], al[4], bx[4];
        #pragma unroll
        for (int mt = 0; mt < 4; ++mt) ah[mt] = *(const short8*)(ra + AH_B + mt * 16 * LDW);
        #pragma unroll
        for (int nt = 0; nt < 4; ++nt) bx[nt] = *(const short8*)(rb + BH_B + nt * 16 * LDW);
        #pragma unroll
        for (int mt = 0; mt < 4; ++mt)
            #pragma unroll
            for (int nt = 0; nt < 4; ++nt)
                acc[mt][nt] = __builtin_amdgcn_mfma_f32_16x16x32_bf16(ah[mt], bx[nt], acc[mt][nt], 0, 0, 0);
        #pragma unroll
        for (int mt = 0; mt < 4; ++mt) al[mt] = *(const short8*)(ra + AL_B + mt * 16 * LDW);
        #pragma unroll
        for (int mt = 0; mt < 4; ++mt)
            #pragma unroll
            for (int nt = 0; nt < 4; ++nt)
                acc[mt][nt] = __builtin_amdgcn_mfma_f32_16x16x32_bf16(al[mt], bx[nt], acc[mt][nt], 0, 0, 0);
        #pragma unroll
        for (int nt = 0; nt < 4; ++nt) bx[nt] = *(const short8*)(rb + BL_B + nt * 16 * LDW);
        #pragma unroll
        for (int mt = 0; mt < 4; ++mt)
            #pragma unroll
            for (int nt = 0; nt < 4; ++nt)
                acc[mt][nt] = __builtin_amdgcn_mfma_f32_16x16x32_bf16(ah[mt], bx[nt], acc[mt][nt], 0, 0, 0);
        __syncthreads();
    }

    #pragma unroll
    for (int mt = 0; mt < 4; ++mt) {
        #pragma unroll
        for (int nt = 0; nt < 4; ++nt) {
            const int r0 = m0 + wm * 64 + mt * 16 + quad * 4;
            const int c0 = n0 + wn * 64 + nt * 16 + lr;
            #pragma unroll
            for (int j = 0; j < 4; ++j)
                C[(size_t)(r0 + j) * KC + c0] = acc[mt][nt][j];
        }
    }
}

// ------------------------------------------------------------ block reduce --
__device__ __forceinline__ float block_reduce_sum(float v, volatile float* sf,
                                                  int lane, int w) {
    #pragma unroll
    for (int off = 32; off; off >>= 1) v += __shfl_xor(v, off, 64);
    if (lane == 0) sf[w] = v;
    __syncthreads();
    v = sf[0] + sf[1] + sf[2] + sf[3];
    __syncthreads();
    return v;
}

// ---------------------------------------------------------------- row pass --
// One row per wave per iteration. NO explicit prefetch; #pragma unroll 1 keeps
// one row of state live (~90 VGPRs, no spill under the 128 cap).
__global__ __launch_bounds__(256, 4) void rowpass(const float* __restrict__ sim,
                                                  float* __restrict__ nn,
                                                  float* __restrict__ divpart2,  // [1024][2048]
                                                  int*   __restrict__ counts,
                                                  float* __restrict__ entpart,   // [1024]
                                                  int*   __restrict__ nflag,
                                                  int*   __restrict__ flags) {
    __shared__ float divp[KC];
    __shared__ float sent[4];
    const int t = threadIdx.x, lane = t & 63, w = t >> 6;
    const int b = blockIdx.x;
    const int row0 = b * 16 + w * 4;
    const int col0 = lane << 2;

    float4 dacc[8] = {};
    float ent_acc = 0.f;
    const float* base = sim + (size_t)row0 * KC + col0;

    #pragma unroll 1
    for (int rr = 0; rr < 4; ++rr) {
        float4 cur[8];
        const float* rp = base + (size_t)rr * KC;
        #pragma unroll
        for (int j = 0; j < 8; ++j) cur[j] = *(const float4*)(rp + 256 * j);

        // ---- top-2 (value, index), first-occurrence tie rule ----
        float bv = -3.0e38f, rv = -3.0e38f;
        int   bi = 0x7fffffff, ri = 0x7fffffff;
        #pragma unroll
        for (int j = 0; j < 8; ++j) {
            #pragma unroll
            for (int c = 0; c < 4; ++c) {
                float v = (&cur[j].x)[c];
                int   i = col0 + c + 256 * j;
                if (v > bv || (v == bv && i < bi)) { rv = bv; ri = bi; bv = v; bi = i; }
                else if (v > rv || (v == rv && i < ri)) { rv = v; ri = i; }
            }
        }
        #pragma unroll
        for (int off = 32; off; off >>= 1) {
            float obv = __shfl_xor(bv, off, 64);
            int   obi = __shfl_xor(bi, off, 64);
            float orv = __shfl_xor(rv, off, 64);
            int   ori = __shfl_xor(ri, off, 64);
            bool ob = (obv > bv) || (obv == bv && obi < bi);
            float c1v = ob ? bv : obv;  int c1i = ob ? bi : obi;
            float c2v = ob ? orv : rv;  int c2i = ob ? ori : ri;
            bv = ob ? obv : bv;  bi = ob ? obi : bi;
            bool rb = (c1v > c2v) || (c1v == c2v && c1i < c2i);
            rv = rb ? c1v : c2v;  ri = rb ? c1i : c2i;
        }
        const float m = bv;

        // ---- softmax stats: Z = sum e, S = sum e*(s-m) ----
        float Z = 0.f, S = 0.f;
        #pragma unroll
        for (int j = 0; j < 8; ++j) {
            #pragma unroll
            for (int c = 0; c < 4; ++c) {
                float d = (&cur[j].x)[c] - m;
                float e = expf(d);
                Z += e; S += e * d;
                (&cur[j].x)[c] = e;
            }
        }
        #pragma unroll
        for (int off = 32; off; off >>= 1) {
            Z += __shfl_xor(Z, off, 64);
            S += __shfl_xor(S, off, 64);
        }
        const float inv = 1.0f / Z;
        #pragma unroll
        for (int j = 0; j < 8; ++j) {
            dacc[j].x += cur[j].x * inv; dacc[j].y += cur[j].y * inv;
            dacc[j].z += cur[j].z * inv; dacc[j].w += cur[j].w * inv;
        }

        if (lane == 0) {
            // sum p*log2(p+1e-8) = log2e*(S/Z) - log2(Z) + 2048*1e-8*log2e
            ent_acc += 1.4426950408889634f * (S * inv) - log2f(Z) + 2.9546393e-5f;
            atomicAdd(&counts[bi], 1);
            nn[row0 + rr] = (float)bi;
            if (bv - rv < FLAG_TAU) {
                int e = atomicAdd(nflag, 1);
                if (e < FLAG_CAP) {
                    flags[3*e] = row0 + rr; flags[3*e+1] = bi; flags[3*e+2] = ri;
                }
            }
        }
    }

    if (lane == 0) sent[w] = ent_acc;
    // deterministic cross-wave diversity combine
    for (int ww = 0; ww < 4; ++ww) {
        if (w == ww) {
            #pragma unroll
            for (int j = 0; j < 8; ++j) {
                float4* p = (float4*)&divp[col0 + 256 * j];
                if (ww == 0) *p = dacc[j];
                else {
                    float4 v = *p;
                    v.x += dacc[j].x; v.y += dacc[j].y;
                    v.z += dacc[j].z; v.w += dacc[j].w;
                    *p = v;
                }
            }
        }
        __syncthreads();
    }
    float4* dst = (float4*)(divpart2 + (size_t)b * KC);
    dst[t]       = *(float4*)&divp[t * 4];
    dst[t + 256] = *(float4*)&divp[t * 4 + 1024];
    if (t == 0) entpart[b] = sent[0] + sent[1] + sent[2] + sent[3];
}

// --------------------------------------------- fixup + fin1a (one launch) ---
// blocks [0,128): column partial sums of divpart2 -> part2[128][2048]
// blocks [128,256): exact fp32 re-check of flagged near-tie rows
__global__ __launch_bounds__(256) void fixfin(const float* __restrict__ divpart2,
                                              float* __restrict__ part2,
                                              const float* __restrict__ A,
                                              const float* __restrict__ B,
                                              float* __restrict__ nn,
                                              int*   __restrict__ counts,
                                              const int* __restrict__ flags,
                                              const int* __restrict__ nflagp) {
    const int t = threadIdx.x;
    if (blockIdx.x < 128) {
        const int b = blockIdx.x;
        const float* dp = divpart2 + (size_t)b * 8 * KC;
        #pragma unroll
        for (int j = 0; j < 8; ++j) {
            int c = t + 256 * j;
            float s = 0.f;
            #pragma unroll
            for (int r = 0; r < 8; ++r) s += dp[(size_t)r * KC + c];
            part2[(size_t)b * KC + c] = s;
        }
    } else {
        __shared__ float sf[4];
        int nf = *nflagp; if (nf > FLAG_CAP) nf = FLAG_CAP;
        const int lane = t & 63, w = t >> 6;
        for (int e = blockIdx.x - 128; e < nf; e += 128) {
            const int row = flags[3*e], i1 = flags[3*e+1], i2 = flags[3*e+2];
            const float* ar = A + (size_t)row * DIM;
            const float* b1 = B + (size_t)i1 * DIM;
            const float* b2 = B + (size_t)i2 * DIM;
            float d1 = ar[t] * b1[t] + ar[t + 256] * b1[t + 256];
            float d2 = ar[t] * b2[t] + ar[t + 256] * b2[t + 256];
            d1 = block_reduce_sum(d1, sf, lane, w);
            d2 = block_reduce_sum(d2, sf, lane, w);
            if (t == 0 && (d2 > d1 || (d2 == d1 && i2 < i1))) {
                nn[row] = (float)i2;
                atomicSub(&counts[i1], 1);
                atomicAdd(&counts[i2], 1);
            }
            __syncthreads();
        }
    }
}

// ------------------------------------------------------------- finalize -----
__global__ __launch_bounds__(256) void fin1b(const float* __restrict__ part2,
                                             float* __restrict__ divlog8) {
    __shared__ float sf[4];
    const int t = threadIdx.x, lane = t & 63, w = t >> 6;
    const int c = blockIdx.x * 256 + t;
    float s = 0.f;
    for (int r = 0; r < 128; ++r) s += part2[(size_t)r * KC + c];
    float d = s * (1.0f / 16384.0f);
    float v = d * log2f(d + 1e-8f);
    float S = block_reduce_sum(v, sf, lane, w);
    if (t == 0) divlog8[blockIdx.x] = S;
}

__global__ __launch_bounds__(256) void fin2(const float* __restrict__ entpart,
                                            const float* __restrict__ divlog8,
                                            float* __restrict__ lossp) {
    __shared__ float sf[4];
    const int t = threadIdx.x, lane = t & 63, w = t >> 6;
    float se = entpart[t] + entpart[t + 256] + entpart[t + 512] + entpart[t + 768];
    float Se = block_reduce_sum(se, sf, lane, w);
    float Sd = block_reduce_sum((t < 8) ? divlog8[t] : 0.f, sf, lane, w);
    if (t == 0)
        lossp[0] = (float)(-(double)Se / 16384.0 + (double)Sd);
}

// ------------------------------------------------------- quantize+epilogue --
__global__ __launch_bounds__(256) void tail(const float* __restrict__ x,
                                            const float* __restrict__ cb,
                                            const float* __restrict__ oldc,
                                            const int*   __restrict__ counts,
                                            const float* __restrict__ lossp,
                                            const int*   __restrict__ train,
                                            const float* __restrict__ nn,
                                            float* __restrict__ out) {
    const int bb = blockIdx.x;
    const int t  = threadIdx.x;
    if (bb < 4096) {
        const int lane = t & 63;
        const int row  = (bb << 2) + (t >> 6);
        const int idx  = (int)nn[row];
        const float* c  = cb + (size_t)idx * DIM;
        const float* xr = x  + (size_t)row * DIM;

        float4 q0 = *(const float4*)(c + lane * 8);
        float4 q1 = *(const float4*)(c + lane * 8 + 4);

        float s = q0.x+q0.y+q0.z+q0.w + q1.x+q1.y+q1.z+q1.w;
        #pragma unroll
        for (int off = 32; off; off >>= 1) s += __shfl_xor(s, off, 64);
        const float mean = s * (1.0f / 512.0f);
        q0.x -= mean; q0.y -= mean; q0.z -= mean; q0.w -= mean;
        q1.x -= mean; q1.y -= mean; q1.z -= mean; q1.w -= mean;

        float ss = q0.x*q0.x+q0.y*q0.y+q0.z*q0.z+q0.w*q0.w
                 + q1.x*q1.x+q1.y*q1.y+q1.z*q1.z+q1.w*q1.w;
        #pragma unroll
        for (int off = 32; off; off >>= 1) ss += __shfl_xor(ss, off, 64);
        const float inv = 1.0f / sqrtf(ss);

        float4 x0 = *(const float4*)(xr + lane * 8);
        float4 x1 = *(const float4*)(xr + lane * 8 + 4);
        float4 o0, o1;
        o0.x = x0.x + (q0.x*inv - x0.x); o0.y = x0.y + (q0.y*inv - x0.y);
        o0.z = x0.z + (q0.z*inv - x0.z); o0.w = x0.w + (q0.w*inv - x0.w);
        o1.x = x1.x + (q1.x*inv - x1.x); o1.y = x1.y + (q1.y*inv - x1.y);
        o1.z = x1.z + (q1.z*inv - x1.z); o1.w = x1.w + (q1.w*inv - x1.w);
        *(float4*)(out + (size_t)row * DIM + lane * 8)     = o0;
        *(float4*)(out + (size_t)row * DIM + lane * 8 + 4) = o1;
    } else {
        const size_t LOSS4 = 33554432ul / 4;
        const size_t CB4   = 1048576ul  / 4;
        size_t i = (size_t)(bb - 4096) * 256 + t;
        if (i < LOSS4) {
            const float l = lossp[0];
            ((float4*)(out + LOSS_OFF))[i] = make_float4(l, l, l, l);
        } else if (i < LOSS4 + CB4) {
            size_t j = i - LOSS4;
            ((float4*)(out + CB_OFF))[j] = ((const float4*)cb)[j];
        } else {
            size_t k = i - LOSS4 - CB4;
            if (k < 2048) {
                float nc = train[0] ? 0.99f * oldc[k] + 0.01f * (float)counts[k]
                                    : oldc[k];
                out[CNT_OFF + k] = nc;
            }
        }
    }
}

// ------------------------------------------------------------------ launch --
extern "C" void kernel_launch(void* const* d_in, const int* in_sizes, int n_in,
                              void* d_out, int out_size, void* d_ws, size_t ws_size,
                              hipStream_t stream) {
    const float* x     = (const float*)d_in[0];
    const float* cb    = (const float*)d_in[1];
    const float* oldc  = (const float*)d_in[2];
    const int*   train = (const int*)d_in[3];
    float* out = (float*)d_out;

    float* sim      = out + LOSS_OFF;
    float* divpart2 = out + Q_OFF;
    float* part2    = out + CB_OFF;
    float* nn       = out + NN_OFF;

    float* lossp   = (float*)d_ws + WS_LOSS;
    int*   counts  = (int*)d_ws   + WS_CNT;
    float* entpart = (float*)d_ws + WS_ENT;
    int*   nflag   = (int*)d_ws   + WS_NFLAG;
    int*   flags   = (int*)d_ws   + WS_FLAGS;
    float* divlog8 = (float*)d_ws + WS_DIVLOG;

    gemm_mfma<<<dim3(KC / 128, NROWS / 128), 256, 0, stream>>>(x, cb, sim, (int*)d_ws);
    rowpass<<<1024, 256, 0, stream>>>(sim, nn, divpart2, counts, entpart, nflag, flags);
    fixfin<<<256, 256, 0, stream>>>(divpart2, part2, x, cb, nn, counts, flags, nflag);
    fin1b<<<8, 256, 0, stream>>>(part2, divlog8);
    fin2<<<1, 256, 0, stream>>>(entpart, divlog8, lossp);
    tail<<<4096 + 33800, 256, 0, stream>>>(x, cb, oldc, counts, lossp, train, nn, out);
}